// Round 7
// baseline (556.688 us; speedup 1.0000x reference)
//
#include <hip/hip_runtime.h>
#include <stdint.h>

#define L_SEQ   2048
#define BATCH   8
#define DMODEL  512
#define DINNER  1024
#define NHEADS  16
#define HEADDIM 64
#define DSTATE  16
#define CONVDIM 1056
#define DINPROJ 2096
#define NPROJ   4192          // 2*DINPROJ
#define NPROJ_P 4224          // padded to 33*128 for guard-free B staging
#define NROWS   (BATCH*L_SEQ) // 16384
#define NCH     16            // scan chunks
#define CHLEN   128           // L_SEQ/NCH
#define XBCW    1072          // xBC (1056) + dt (16) columns, bf16 buffer width

typedef __attribute__((ext_vector_type(8))) short short8;
typedef __attribute__((ext_vector_type(4))) float f32x4;

static __device__ __forceinline__ unsigned short f2bf(float f) {
    unsigned int u = __float_as_uint(f);
    u += 0x7FFF + ((u >> 16) & 1);
    return (unsigned short)(u >> 16);
}
static __device__ __forceinline__ float bf2f(unsigned short u) {
    return __uint_as_float((unsigned int)u << 16);
}
static __device__ __forceinline__ float silu(float v) {
    return v / (1.f + __expf(-v));
}
// async global->LDS, 16 B per lane; lds base must be wave-uniform
static __device__ __forceinline__ void glds16(const unsigned short* g, unsigned short* l) {
    __builtin_amdgcn_global_load_lds(
        (const __attribute__((address_space(1))) unsigned int*)g,
        (__attribute__((address_space(3))) unsigned int*)l, 16, 0, 0);
}

// ---------------- merged prepack: x->bf16, W1 concat+pad, W2 concat ----------------
#define PREP_N1 (NROWS*DMODEL)        // 8388608
#define PREP_N2 (NPROJ_P*DMODEL)      // 2162688
#define PREP_N3 (512*2048)            // 1048576
__global__ void k_prep(const float* __restrict__ x,
                       const float* __restrict__ fwi, const float* __restrict__ bwi,
                       const float* __restrict__ fow, const float* __restrict__ bow,
                       unsigned short* __restrict__ XB, unsigned short* __restrict__ W1,
                       unsigned short* __restrict__ W2) {
    int i = blockIdx.x * 256 + threadIdx.x;
    if (i < PREP_N1) {
        XB[i] = f2bf(x[i]);
    } else if (i < PREP_N1 + PREP_N2) {
        int j = i - PREP_N1;
        const int FS = DINPROJ * DMODEL;
        W1[j] = (j < 2 * FS) ? f2bf(j < FS ? fwi[j] : bwi[j - FS]) : 0;
    } else if (i < PREP_N1 + PREP_N2 + PREP_N3) {
        int j = i - PREP_N1 - PREP_N2;
        int n = j >> 11, k = j & 2047;
        float v = (k < DINNER) ? fow[n * DINNER + k] : bow[n * DINNER + k - DINNER];
        W2[j] = f2bf(v);
    }
}

// ---------------- bf16 MFMA GEMM core: stage-ahead ping-pong pipeline ----------------
// bm, bn, koff must be declared before the macro is invoked.
#define BM 128
#define BN 128
#define BK 32

#define GEMM_BODY(NROUNDS, EPILOGUE)                                                        \
    __shared__ __align__(16) unsigned short as[2][BM][BK];                                  \
    __shared__ __align__(16) unsigned short bs[2][BN][BK];                                  \
    const int tid = threadIdx.x;                                                            \
    const int lane = tid & 63;                                                              \
    const int wave = tid >> 6;                                                              \
    const int wm = (wave & 1) * 64;                                                         \
    const int wn = (wave >> 1) * 64;                                                        \
    const int l16 = lane & 15;                                                              \
    const int q = lane >> 4;                                                                \
    const int sr = wave * 32;                                                               \
    const int lr = lane >> 2;                                                               \
    const int lc = (lane & 3) * 8;                                                          \
    f32x4 acc[4][4];                                                                        \
    for (int i = 0; i < 4; i++)                                                             \
        for (int j = 0; j < 4; j++) acc[i][j] = (f32x4){0.f, 0.f, 0.f, 0.f};                \
    const unsigned short* Ab = A + (size_t)(bm + sr + lr) * K + koff + lc;                  \
    const unsigned short* Bb = Bw + (size_t)(bn + sr + lr) * K + koff + lc;                 \
    glds16(Ab, &as[0][sr][0]);                                                              \
    glds16(Ab + (size_t)16 * K, &as[0][sr + 16][0]);                                        \
    glds16(Bb, &bs[0][sr][0]);                                                              \
    glds16(Bb + (size_t)16 * K, &bs[0][sr + 16][0]);                                        \
    __syncthreads();                                                                        \
    for (int r = 0; r < NROUNDS; r++) {                                                     \
        const int pb = r & 1;                                                               \
        if (r + 1 < NROUNDS) {  /* stage next round BEFORE consuming current */             \
            const int kb = (r + 1) * BK;                                                    \
            glds16(Ab + kb, &as[pb ^ 1][sr][0]);                                            \
            glds16(Ab + (size_t)16 * K + kb, &as[pb ^ 1][sr + 16][0]);                      \
            glds16(Bb + kb, &bs[pb ^ 1][sr][0]);                                            \
            glds16(Bb + (size_t)16 * K + kb, &bs[pb ^ 1][sr + 16][0]);                      \
        }                                                                                   \
        short8 af[4], bfr[4];                                                               \
        for (int i = 0; i < 4; i++) af[i] = *(const short8*)&as[pb][wm + i * 16 + l16][q * 8]; \
        for (int j = 0; j < 4; j++) bfr[j] = *(const short8*)&bs[pb][wn + j * 16 + l16][q * 8]; \
        for (int i = 0; i < 4; i++)                                                         \
            for (int j = 0; j < 4; j++)                                                     \
                acc[i][j] = __builtin_amdgcn_mfma_f32_16x16x32_bf16(af[i], bfr[j], acc[i][j], 0, 0, 0); \
        __syncthreads();  /* drains stage(r+1) overlapped with the MFMAs above */           \
    }                                                                                       \
    EPILOGUE

// in_proj GEMM: XCD-swizzled 1D grid (8*16*33 = 4224 blocks), K=512 -> 16 rounds.
__global__ __launch_bounds__(256) void k_gemm_proj(const unsigned short* __restrict__ A,
                                                   const unsigned short* __restrict__ Bw,
                                                   unsigned short* __restrict__ ZG,
                                                   unsigned short* __restrict__ XBCDT) {
    const int K = DMODEL;
    const int N = NPROJ;
    const int lin = blockIdx.x;
    const int xcd = lin & 7;
    const int idx = lin >> 3;
    const int mloc = idx & 15;
    const int n_tile = idx >> 4;        // 0..32
    const int bm = (mloc * 8 + xcd) * BM;
    const int bn = n_tile * BN;
    const int koff = 0;
    GEMM_BODY(16, {
        for (int i = 0; i < 4; i++) {
            int row0 = bm + wm + i * 16 + q * 4;
            for (int j = 0; j < 4; j++) {
                int col = bn + wn + j * 16 + l16;
                if (col < N) {
                    int dir = col >= DINPROJ;
                    int cc = col - dir * DINPROJ;
                    for (int r = 0; r < 4; r++) {
                        unsigned short v = f2bf(acc[i][j][r]);
                        size_t rowo = (size_t)(dir * NROWS + row0 + r);
                        if (cc < DINNER)
                            ZG[rowo * DINNER + cc] = v;
                        else
                            XBCDT[rowo * XBCW + (cc - DINNER)] = v;
                    }
                }
            }
        }
    })
}

// out_proj GEMM: split-K=2, XCD-swizzled (1024 blocks), each half K=1024 -> 32 rounds.
// ksplit 0 -> C0 (d_out), ksplit 1 -> C1 (partial buffer).
__global__ __launch_bounds__(256) void k_gemm_out(const unsigned short* __restrict__ A,
                                                  const unsigned short* __restrict__ Bw,
                                                  float* __restrict__ C0,
                                                  float* __restrict__ C1) {
    const int K = 2048;
    const int N = 512;
    const int lin = blockIdx.x;
    const int xcd = lin & 7;
    const int idx = lin >> 3;           // 0..127
    const int ksplit = idx >> 6;        // 0..1
    const int rem = idx & 63;
    const int g = rem >> 4;             // 4 groups
    const int r2 = rem & 15;
    const int n_tile = r2 >> 2;         // 0..3
    const int mloc = (g << 2) | (r2 & 3);
    const int bm = (mloc * 8 + xcd) * BM;
    const int bn = n_tile * BN;
    const int koff = ksplit * 1024;
    float* __restrict__ C = ksplit ? C1 : C0;
    GEMM_BODY(32, {
        for (int i = 0; i < 4; i++) {
            int row0 = bm + wm + i * 16 + q * 4;
            for (int j = 0; j < 4; j++) {
                int col = bn + wn + j * 16 + l16;
                for (int r = 0; r < 4; r++)
                    C[(size_t)(row0 + r) * N + col] = acc[i][j][r];
            }
        }
    })
}

// final add of split-K partial into d_out
__global__ void k_addout(float* __restrict__ C0, const float* __restrict__ C1) {
    int i = blockIdx.x * 256 + threadIdx.x;   // over f32x4 groups: 16384*512/4
    if (i < NROWS * 512 / 4) {
        f32x4 a = *(const f32x4*)&C0[i * 4];
        f32x4 b = *(const f32x4*)&C1[i * 4];
        a += b;
        *(f32x4*)&C0[i * 4] = a;
    }
}

// ---------------- LDS-tiled depthwise causal conv + silu ----------------
__global__ __launch_bounds__(256) void k_conv2(const unsigned short* __restrict__ XBCDT,
                                               const float* __restrict__ fw_w, const float* __restrict__ fw_b,
                                               const float* __restrict__ bw_w, const float* __restrict__ bw_b,
                                               unsigned short* __restrict__ XS, float* __restrict__ BCb) {
    __shared__ unsigned short sm[70][256];  // rows l0-3 .. l0+66
    int t = threadIdx.x;
    int bidx = blockIdx.x;
    int lcn = bidx & 31;
    int b   = (bidx >> 5) & 7;
    int dir = (bidx >> 8) & 1;
    int ct  = bidx >> 9;
    int c0 = ct * 256;
    int l0 = lcn * 64;
    int c = c0 + t;
    const unsigned short* src = XBCDT + (size_t)dir * NROWS * XBCW;
    bool cok = (c < CONVDIM);
#pragma unroll 2
    for (int r = 0; r < 70; r++) {
        int li = l0 - 3 + r;
        unsigned short v = 0;
        if (li >= 0 && li < L_SEQ && cok)
            v = src[(size_t)((b << 11) + li) * XBCW + c];
        sm[r][t] = v;
    }
    __syncthreads();
    if (!cok) return;
    const float* w = (dir ? bw_w : fw_w) + c * 4;
    float bias = (dir ? bw_b : fw_b)[c];
    float wr[4];
    if (dir) { wr[0] = w[3]; wr[1] = w[2]; wr[2] = w[1]; wr[3] = w[0]; }
    else     { wr[0] = w[0]; wr[1] = w[1]; wr[2] = w[2]; wr[3] = w[3]; }
    int o = dir ? 3 : 0;
    float w0 = bf2f(sm[o][t]), w1 = bf2f(sm[o + 1][t]), w2 = bf2f(sm[o + 2][t]);
    unsigned short* xso = XS + (size_t)dir * NROWS * DINNER;
    float* bco = BCb + (size_t)dir * NROWS * 32;
    int rowbase = (b << 11) + l0;
#pragma unroll 4
    for (int l = 0; l < 64; l++) {
        float w3 = bf2f(sm[l + o + 3][t]);
        float acc = ((wr[0] * w0 + wr[1] * w1) + (wr[2] * w2 + wr[3] * w3)) + bias;
        float v = silu(acc);
        int row = rowbase + l;
        if (c < DINNER)
            xso[(size_t)row * DINNER + c] = f2bf(v);
        else
            bco[(size_t)row * 32 + (c - DINNER)] = v;
        w0 = w1; w1 = w2; w2 = w3;
    }
}

// ---------------- dt/dA precompute ----------------
__global__ void k_dt(const unsigned short* __restrict__ XBCDT,
                     const float* __restrict__ fdtb, const float* __restrict__ fAl,
                     const float* __restrict__ bdtb, const float* __restrict__ bAl,
                     float* __restrict__ DT, float* __restrict__ DA) {
    int gid = blockIdx.x * 256 + threadIdx.x;
    if (gid >= 2 * NROWS * NHEADS) return;
    int h = gid & 15;
    int row = (gid >> 4) & (NROWS - 1);
    int dir = gid >> 18;
    float dtb = (dir ? bdtb : fdtb)[h];
    float Al = (dir ? bAl : fAl)[h];
    float x = bf2f(XBCDT[(size_t)(dir * NROWS + row) * XBCW + CONVDIM + h]) + dtb;
    float dt = (x > 15.f) ? x : log1pf(__expf(x));
    float dA = __expf(-__expf(Al) * dt);
    DT[gid] = dt;
    DA[gid] = dA;
}

// ---------------- scan pass A: per-chunk local state + decay product ----------------
__global__ __launch_bounds__(64) void k_scan_state(const unsigned short* __restrict__ XS,
                                                   const float* __restrict__ BCb,
                                                   const float* __restrict__ DT,
                                                   const float* __restrict__ DA,
                                                   float* __restrict__ S, float* __restrict__ P) {
    int idx = blockIdx.x;  // (((dir*8+b)*16+h)*16+chunk)
    int c = idx & 15, h = (idx >> 4) & 15, b = (idx >> 8) & 7, dir = idx >> 11;
    int p = threadIdx.x;
    const unsigned short* xs = XS + (size_t)dir * NROWS * DINNER;
    const float* bc = BCb + (size_t)dir * NROWS * 32;
    const float* dtp = DT + (size_t)dir * NROWS * NHEADS;
    const float* dap = DA + (size_t)dir * NROWS * NHEADS;
    float hreg[16];
#pragma unroll
    for (int n = 0; n < 16; n++) hreg[n] = 0.f;
    float Pp = 1.f;
#pragma unroll 4
    for (int tl = 0; tl < CHLEN; ++tl) {
        int t = c * CHLEN + tl;
        int l = dir ? (L_SEQ - 1 - t) : t;
        int row = (b << 11) + l;
        float xv = bf2f(xs[(size_t)row * DINNER + h * HEADDIM + p]);
        float dt = dtp[row * 16 + h];
        float dA = dap[row * 16 + h];
        f32x4 Bv[4];
#pragma unroll
        for (int qq = 0; qq < 4; qq++) Bv[qq] = *(const f32x4*)&bc[(size_t)row * 32 + qq * 4];
        float kk = dt * xv;
#pragma unroll
        for (int n = 0; n < 16; n++) hreg[n] = fmaf(hreg[n], dA, kk * Bv[n >> 2][n & 3]);
        Pp *= dA;
    }
#pragma unroll
    for (int qq = 0; qq < 4; qq++) {
        f32x4 v = {hreg[qq * 4], hreg[qq * 4 + 1], hreg[qq * 4 + 2], hreg[qq * 4 + 3]};
        *(f32x4*)&S[(size_t)idx * 1024 + p * 16 + qq * 4] = v;
    }
    if (p == 0) P[idx] = Pp;
}

// ---------------- scan pass B: combine chunk states IN PLACE (S -> Hinit) --------
__global__ void k_combine(float* __restrict__ S, const float* __restrict__ P) {
    int gid = blockIdx.x * 256 + threadIdx.x;  // 2*8*16*1024 = 262144
    if (gid >= 2 * 8 * 16 * 1024) return;
    int pn = gid & 1023;
    int base = gid >> 10;
    float H = 0.f;
#pragma unroll 4
    for (int c = 0; c < NCH; c++) {
        size_t o = ((size_t)base * NCH + c) * 1024 + pn;
        float s = S[o];   // read BEFORE overwrite
        S[o] = H;         // S becomes Hinit
        H = H * P[base * NCH + c] + s;
    }
}

// ---------------- scan pass C: replay with init state, emit y (bf16, aliases XS) ----
__global__ __launch_bounds__(64) void k_scan_out(const unsigned short* __restrict__ XS,
                                                 const float* __restrict__ BCb,
                                                 const float* __restrict__ DT,
                                                 const float* __restrict__ DA,
                                                 const float* __restrict__ Hinit,
                                                 const float* __restrict__ fDp,
                                                 const float* __restrict__ bDp,
                                                 unsigned short* __restrict__ Y) {
    int idx = blockIdx.x;
    int c = idx & 15, h = (idx >> 4) & 15, b = (idx >> 8) & 7, dir = idx >> 11;
    int p = threadIdx.x;
    const unsigned short* xs = XS + (size_t)dir * NROWS * DINNER;
    const float* bc = BCb + (size_t)dir * NROWS * 32;
    const float* dtp = DT + (size_t)dir * NROWS * NHEADS;
    const float* dap = DA + (size_t)dir * NROWS * NHEADS;
    unsigned short* yo = Y + (size_t)dir * NROWS * DINNER;
    float Dpv = (dir ? bDp : fDp)[h];
    float hreg[16];
#pragma unroll
    for (int qq = 0; qq < 4; qq++) {
        f32x4 v = *(const f32x4*)&Hinit[(size_t)idx * 1024 + p * 16 + qq * 4];
#pragma unroll
        for (int e = 0; e < 4; e++) hreg[qq * 4 + e] = v[e];
    }
#pragma unroll 4
    for (int tl = 0; tl < CHLEN; ++tl) {
        int t = c * CHLEN + tl;
        int l = dir ? (L_SEQ - 1 - t) : t;
        int row = (b << 11) + l;
        float xv = bf2f(xs[(size_t)row * DINNER + h * HEADDIM + p]);
        float dt = dtp[row * 16 + h];
        float dA = dap[row * 16 + h];
        f32x4 Bv[4], Cv[4];
#pragma unroll
        for (int qq = 0; qq < 4; qq++) Bv[qq] = *(const f32x4*)&bc[(size_t)row * 32 + qq * 4];
#pragma unroll
        for (int qq = 0; qq < 4; qq++) Cv[qq] = *(const f32x4*)&bc[(size_t)row * 32 + 16 + qq * 4];
        float kk = dt * xv;
        float y = 0.f;
#pragma unroll
        for (int n = 0; n < 16; n++) {
            hreg[n] = fmaf(hreg[n], dA, kk * Bv[n >> 2][n & 3]);
            y = fmaf(hreg[n], Cv[n >> 2][n & 3], y);
        }
        yo[(size_t)row * DINNER + h * HEADDIM + p] = f2bf(y + xv * Dpv);
    }
}

// ---------------- gated RMSNorm -> bf16 concat ----------------
__global__ __launch_bounds__(256) void k_gatenorm(const unsigned short* __restrict__ Y,
                                                  const unsigned short* __restrict__ ZG,
                                                  const float* __restrict__ fnw,
                                                  const float* __restrict__ bnw,
                                                  unsigned short* __restrict__ NRM) {
    int bid = blockIdx.x;
    int dir = bid >> 14;
    int row = bid & (NROWS - 1);
    int tid = threadIdx.x;
    int c = tid * 4;
    ushort4 yu = *(const ushort4*)&Y[(size_t)(dir * NROWS + row) * DINNER + c];
    ushort4 zu = *(const ushort4*)&ZG[(size_t)(dir * NROWS + row) * DINNER + c];
    float v0 = bf2f(yu.x) * silu(bf2f(zu.x));
    float v1 = bf2f(yu.y) * silu(bf2f(zu.y));
    float v2 = bf2f(yu.z) * silu(bf2f(zu.z));
    float v3 = bf2f(yu.w) * silu(bf2f(zu.w));
    float ss = v0 * v0 + v1 * v1 + v2 * v2 + v3 * v3;
#pragma unroll
    for (int off = 32; off > 0; off >>= 1) ss += __shfl_down(ss, off);
    __shared__ float red[4];
    if ((tid & 63) == 0) red[tid >> 6] = ss;
    __syncthreads();
    float tot = red[0] + red[1] + red[2] + red[3];
    float scale = rsqrtf(tot * (1.f / 1024.f) + 1e-5f);
    const float* nw = dir ? bnw : fnw;
    ushort4 o;
    o.x = f2bf(v0 * scale * nw[c]);
    o.y = f2bf(v1 * scale * nw[c + 1]);
    o.z = f2bf(v2 * scale * nw[c + 2]);
    o.w = f2bf(v3 * scale * nw[c + 3]);
    *(ushort4*)&NRM[(size_t)row * 2048 + dir * DINNER + c] = o;
}

// ---------------- host launch ----------------
extern "C" void kernel_launch(void* const* d_in, const int* in_sizes, int n_in,
                              void* d_out, int out_size, void* d_ws, size_t ws_size,
                              hipStream_t stream) {
    const float* x     = (const float*)d_in[0];
    const float* f_inw = (const float*)d_in[1];
    const float* f_cw  = (const float*)d_in[2];
    const float* f_cb  = (const float*)d_in[3];
    const float* f_dtb = (const float*)d_in[4];
    const float* f_Al  = (const float*)d_in[5];
    const float* f_Dp  = (const float*)d_in[6];
    const float* f_nw  = (const float*)d_in[7];
    const float* f_ow  = (const float*)d_in[8];
    const float* b_inw = (const float*)d_in[9];
    const float* b_cw  = (const float*)d_in[10];
    const float* b_cb  = (const float*)d_in[11];
    const float* b_dtb = (const float*)d_in[12];
    const float* b_Al  = (const float*)d_in[13];
    const float* b_Dp  = (const float*)d_in[14];
    const float* b_nw  = (const float*)d_in[15];
    const float* b_ow  = (const float*)d_in[16];

    char* ws = (char*)d_ws;
    size_t off = 0;
    auto alloc = [&](size_t bytes) {
        void* p = ws + off;
        off += (bytes + 255) & ~(size_t)255;
        return p;
    };
    // --- persistent-phase buffers ---
    // union: XBCDT (in_proj -> conv/dt) / NRM (gatenorm -> out GEMM)
    unsigned short* XBCDT = (unsigned short*)alloc((size_t)2 * NROWS * XBCW * 2);   // 70.3 MB
    unsigned short* NRM   = XBCDT;  // 67.1 MB <= 70.3 MB, disjoint lifetime
    // union: XS (conv -> scans) / Y (scan C writes over XS element-after-read)
    unsigned short* XS    = (unsigned short*)alloc((size_t)2 * NROWS * DINNER * 2); // 67.1 MB
    unsigned short* Yb    = XS;
    // union: ZG (in_proj -> gatenorm) / PBUF split-K partial (gemm_out -> addout)
    unsigned short* ZG    = (unsigned short*)alloc((size_t)2 * NROWS * DINNER * 2); // 67.1 MB
    float* PBUF = (float*)ZG;       // 33.5 MB <= 67.1 MB, disjoint lifetime
    unsigned short* W2    = (unsigned short*)alloc((size_t)512 * 2048 * 2);         //  2.1 MB
    float* BCb  = (float*)alloc((size_t)2 * NROWS * 32 * 4);                        //  4.2 MB
    float* DT   = (float*)alloc((size_t)2 * NROWS * NHEADS * 4);                    //  2.1 MB
    float* DA   = (float*)alloc((size_t)2 * NROWS * NHEADS * 4);                    //  2.1 MB
    // union: {XB, W1} (phases 0-1) / {S, P} (phase 4) — disjoint lifetimes
    char* unionBase = (char*)alloc((size_t)16777216 + (size_t)NPROJ_P * DMODEL * 2); // 21.1 MB
    unsigned short* XB = (unsigned short*)unionBase;
    unsigned short* W1 = (unsigned short*)(unionBase + 16777216);
    float* S = (float*)unionBase;                    // 16.8 MB (Hinit in-place)
    float* P = (float*)(unionBase + 16777216);       // 16 KB
    // total: ~236 MB

    if (ws_size < off) return;  // defensive: fail cleanly (wrong answer) instead of faulting

    // 1. merged prepack
    {
        int n = PREP_N1 + PREP_N2 + PREP_N3;
        k_prep<<<(n + 255) / 256, 256, 0, stream>>>(x, f_inw, b_inw, f_ow, b_ow, XB, W1, W2);
    }
    // 2. in_proj GEMM (both dirs), XCD-swizzled pipelined, routed bf16 epilogue
    k_gemm_proj<<<8 * 16 * 33, 256, 0, stream>>>(XB, W1, ZG, XBCDT);
    // 3. LDS-tiled conv + dt prep
    k_conv2<<<5 * 2 * 8 * 32, 256, 0, stream>>>(XBCDT, f_cw, f_cb, b_cw, b_cb, XS, BCb);
    {
        int n = 2 * NROWS * NHEADS;
        k_dt<<<(n + 255) / 256, 256, 0, stream>>>(XBCDT, f_dtb, f_Al, b_dtb, b_Al, DT, DA);
    }
    // 4. chunked scan (S written over dead XB/W1 region; combine is in-place)
    k_scan_state<<<2 * 8 * 16 * NCH, 64, 0, stream>>>(XS, BCb, DT, DA, S, P);
    {
        int n = 2 * 8 * 16 * 1024;
        k_combine<<<(n + 255) / 256, 256, 0, stream>>>(S, P);
    }
    k_scan_out<<<2 * 8 * 16 * NCH, 64, 0, stream>>>(XS, BCb, DT, DA, S, f_Dp, b_Dp, Yb);
    // 5. gated RMSNorm -> bf16 (writes NRM over dead XBCDT region)
    k_gatenorm<<<2 * NROWS, 256, 0, stream>>>(Yb, ZG, f_nw, b_nw, NRM);
    // 6. out_proj GEMM split-K=2 (partial into dead ZG region), then add
    k_gemm_out<<<8 * 128, 256, 0, stream>>>(NRM, W2, (float*)d_out, PBUF);
    {
        int n = NROWS * 512 / 4;
        k_addout<<<(n + 255) / 256, 256, 0, stream>>>((float*)d_out, PBUF);
    }
}

// Round 8
// 551.130 us; speedup vs baseline: 1.0101x; 1.0101x over previous
//
#include <hip/hip_runtime.h>
#include <stdint.h>

#define L_SEQ   2048
#define BATCH   8
#define DMODEL  512
#define DINNER  1024
#define NHEADS  16
#define HEADDIM 64
#define DSTATE  16
#define CONVDIM 1056
#define DINPROJ 2096
#define NPROJ   4192          // 2*DINPROJ
#define NPROJ_P 4224          // padded to 33*128 for guard-free B staging
#define NROWS   (BATCH*L_SEQ) // 16384
#define NCH     16            // scan chunks
#define CHLEN   128           // L_SEQ/NCH
#define XBCW    1072          // xBC (1056) + dt (16) columns, bf16 buffer width

typedef __attribute__((ext_vector_type(8))) short short8;
typedef __attribute__((ext_vector_type(4))) float f32x4;

static __device__ __forceinline__ unsigned short f2bf(float f) {
    unsigned int u = __float_as_uint(f);
    u += 0x7FFF + ((u >> 16) & 1);
    return (unsigned short)(u >> 16);
}
static __device__ __forceinline__ float bf2f(unsigned short u) {
    return __uint_as_float((unsigned int)u << 16);
}
static __device__ __forceinline__ float silu(float v) {
    return v / (1.f + __expf(-v));
}
// async global->LDS, 16 B per lane; lds base must be wave-uniform
static __device__ __forceinline__ void glds16(const unsigned short* g, unsigned short* l) {
    __builtin_amdgcn_global_load_lds(
        (const __attribute__((address_space(1))) unsigned int*)g,
        (__attribute__((address_space(3))) unsigned int*)l, 16, 0, 0);
}

// ---------------- merged prepack: x->bf16, W1 concat+pad, W2 concat ----------------
#define PREP_N1 (NROWS*DMODEL)        // 8388608
#define PREP_N2 (NPROJ_P*DMODEL)      // 2162688
#define PREP_N3 (512*2048)            // 1048576
__global__ void k_prep(const float* __restrict__ x,
                       const float* __restrict__ fwi, const float* __restrict__ bwi,
                       const float* __restrict__ fow, const float* __restrict__ bow,
                       unsigned short* __restrict__ XB, unsigned short* __restrict__ W1,
                       unsigned short* __restrict__ W2) {
    int i = blockIdx.x * 256 + threadIdx.x;
    if (i < PREP_N1) {
        XB[i] = f2bf(x[i]);
    } else if (i < PREP_N1 + PREP_N2) {
        int j = i - PREP_N1;
        const int FS = DINPROJ * DMODEL;
        W1[j] = (j < 2 * FS) ? f2bf(j < FS ? fwi[j] : bwi[j - FS]) : 0;
    } else if (i < PREP_N1 + PREP_N2 + PREP_N3) {
        int j = i - PREP_N1 - PREP_N2;
        int n = j >> 11, k = j & 2047;
        float v = (k < DINNER) ? fow[n * DINNER + k] : bow[n * DINNER + k - DINNER];
        W2[j] = f2bf(v);
    }
}

// ---------------- bf16 MFMA GEMM core: 64x128 tile, 4 waves of 32x64 ----------------
// Small accumulator (32 AGPR/wave) -> ~5 blocks/CU so independent blocks' barriers
// overlap each other's vmcnt drains. bm, bn, koff declared before macro invocation.
#define BM 64
#define BN 128
#define BK 32

#define GEMM_BODY(NROUNDS, EPILOGUE)                                                        \
    __shared__ __align__(16) unsigned short as[2][BM][BK];                                  \
    __shared__ __align__(16) unsigned short bs[2][BN][BK];                                  \
    const int tid = threadIdx.x;                                                            \
    const int lane = tid & 63;                                                              \
    const int wave = tid >> 6;                                                              \
    const int wm = (wave & 1) * 32;                                                         \
    const int wn = (wave >> 1) * 64;                                                        \
    const int l16 = lane & 15;                                                              \
    const int q = lane >> 4;                                                                \
    const int sra = wave * 16;                                                              \
    const int srb = wave * 32;                                                              \
    const int lr = lane >> 2;                                                               \
    const int lc = (lane & 3) * 8;                                                          \
    f32x4 acc[2][4];                                                                        \
    for (int i = 0; i < 2; i++)                                                             \
        for (int j = 0; j < 4; j++) acc[i][j] = (f32x4){0.f, 0.f, 0.f, 0.f};                \
    const unsigned short* Ab = A + (size_t)(bm + sra + lr) * K + koff + lc;                 \
    const unsigned short* Bb = Bw + (size_t)(bn + srb + lr) * K + koff + lc;                \
    glds16(Ab, &as[0][sra][0]);                                                             \
    glds16(Bb, &bs[0][srb][0]);                                                             \
    glds16(Bb + (size_t)16 * K, &bs[0][srb + 16][0]);                                       \
    __syncthreads();                                                                        \
    for (int r = 0; r < NROUNDS; r++) {                                                     \
        const int pb = r & 1;                                                               \
        if (r + 1 < NROUNDS) {  /* stage next round BEFORE consuming current */             \
            const int kb = (r + 1) * BK;                                                    \
            glds16(Ab + kb, &as[pb ^ 1][sra][0]);                                           \
            glds16(Bb + kb, &bs[pb ^ 1][srb][0]);                                           \
            glds16(Bb + (size_t)16 * K + kb, &bs[pb ^ 1][srb + 16][0]);                     \
        }                                                                                   \
        short8 af[2], bfr[4];                                                               \
        for (int i = 0; i < 2; i++) af[i] = *(const short8*)&as[pb][wm + i * 16 + l16][q * 8]; \
        for (int j = 0; j < 4; j++) bfr[j] = *(const short8*)&bs[pb][wn + j * 16 + l16][q * 8]; \
        for (int i = 0; i < 2; i++)                                                         \
            for (int j = 0; j < 4; j++)                                                     \
                acc[i][j] = __builtin_amdgcn_mfma_f32_16x16x32_bf16(af[i], bfr[j], acc[i][j], 0, 0, 0); \
        __syncthreads();  /* drain of stage(r+1) overlaps other resident blocks */          \
    }                                                                                       \
    EPILOGUE

// in_proj GEMM: XCD-swizzled 1D grid (8*32*33 = 8448 blocks), K=512 -> 16 rounds.
__global__ __launch_bounds__(256) void k_gemm_proj(const unsigned short* __restrict__ A,
                                                   const unsigned short* __restrict__ Bw,
                                                   unsigned short* __restrict__ ZG,
                                                   unsigned short* __restrict__ XBCDT) {
    const int K = DMODEL;
    const int N = NPROJ;
    const int lin = blockIdx.x;
    const int xcd = lin & 7;
    const int idx = lin >> 3;
    const int mloc = idx & 31;
    const int n_tile = idx >> 5;        // 0..32
    const int bm = (mloc * 8 + xcd) * BM;
    const int bn = n_tile * BN;
    const int koff = 0;
    GEMM_BODY(16, {
        for (int i = 0; i < 2; i++) {
            int row0 = bm + wm + i * 16 + q * 4;
            for (int j = 0; j < 4; j++) {
                int col = bn + wn + j * 16 + l16;
                if (col < N) {
                    int dir = col >= DINPROJ;
                    int cc = col - dir * DINPROJ;
                    for (int r = 0; r < 4; r++) {
                        unsigned short v = f2bf(acc[i][j][r]);
                        size_t rowo = (size_t)(dir * NROWS + row0 + r);
                        if (cc < DINNER)
                            ZG[rowo * DINNER + cc] = v;
                        else
                            XBCDT[rowo * XBCW + (cc - DINNER)] = v;
                    }
                }
            }
        }
    })
}

// out_proj GEMM: XCD-swizzled (8*32*4 = 1024 blocks), K=2048 -> 64 rounds, no split-K.
__global__ __launch_bounds__(256) void k_gemm_out(const unsigned short* __restrict__ A,
                                                  const unsigned short* __restrict__ Bw,
                                                  float* __restrict__ C) {
    const int K = 2048;
    const int lin = blockIdx.x;
    const int xcd = lin & 7;
    const int idx = lin >> 3;
    const int mloc = idx & 31;
    const int n_tile = idx >> 5;        // 0..3
    const int bm = (mloc * 8 + xcd) * BM;
    const int bn = n_tile * BN;
    const int koff = 0;
    GEMM_BODY(64, {
        for (int i = 0; i < 2; i++) {
            int row0 = bm + wm + i * 16 + q * 4;
            for (int j = 0; j < 4; j++) {
                int col = bn + wn + j * 16 + l16;
                for (int r = 0; r < 4; r++)
                    C[(size_t)(row0 + r) * 512 + col] = acc[i][j][r];
            }
        }
    })
}

// ---------------- LDS-tiled depthwise causal conv + silu ----------------
__global__ __launch_bounds__(256) void k_conv2(const unsigned short* __restrict__ XBCDT,
                                               const float* __restrict__ fw_w, const float* __restrict__ fw_b,
                                               const float* __restrict__ bw_w, const float* __restrict__ bw_b,
                                               unsigned short* __restrict__ XS, float* __restrict__ BCb) {
    __shared__ unsigned short sm[70][256];  // rows l0-3 .. l0+66
    int t = threadIdx.x;
    int bidx = blockIdx.x;
    int lcn = bidx & 31;
    int b   = (bidx >> 5) & 7;
    int dir = (bidx >> 8) & 1;
    int ct  = bidx >> 9;
    int c0 = ct * 256;
    int l0 = lcn * 64;
    int c = c0 + t;
    const unsigned short* src = XBCDT + (size_t)dir * NROWS * XBCW;
    bool cok = (c < CONVDIM);
#pragma unroll 2
    for (int r = 0; r < 70; r++) {
        int li = l0 - 3 + r;
        unsigned short v = 0;
        if (li >= 0 && li < L_SEQ && cok)
            v = src[(size_t)((b << 11) + li) * XBCW + c];
        sm[r][t] = v;
    }
    __syncthreads();
    if (!cok) return;
    const float* w = (dir ? bw_w : fw_w) + c * 4;
    float bias = (dir ? bw_b : fw_b)[c];
    float wr[4];
    if (dir) { wr[0] = w[3]; wr[1] = w[2]; wr[2] = w[1]; wr[3] = w[0]; }
    else     { wr[0] = w[0]; wr[1] = w[1]; wr[2] = w[2]; wr[3] = w[3]; }
    int o = dir ? 3 : 0;
    float w0 = bf2f(sm[o][t]), w1 = bf2f(sm[o + 1][t]), w2 = bf2f(sm[o + 2][t]);
    unsigned short* xso = XS + (size_t)dir * NROWS * DINNER;
    float* bco = BCb + (size_t)dir * NROWS * 32;
    int rowbase = (b << 11) + l0;
#pragma unroll 4
    for (int l = 0; l < 64; l++) {
        float w3 = bf2f(sm[l + o + 3][t]);
        float acc = ((wr[0] * w0 + wr[1] * w1) + (wr[2] * w2 + wr[3] * w3)) + bias;
        float v = silu(acc);
        int row = rowbase + l;
        if (c < DINNER)
            xso[(size_t)row * DINNER + c] = f2bf(v);
        else
            bco[(size_t)row * 32 + (c - DINNER)] = v;
        w0 = w1; w1 = w2; w2 = w3;
    }
}

// ---------------- dt/dA precompute ----------------
__global__ void k_dt(const unsigned short* __restrict__ XBCDT,
                     const float* __restrict__ fdtb, const float* __restrict__ fAl,
                     const float* __restrict__ bdtb, const float* __restrict__ bAl,
                     float* __restrict__ DT, float* __restrict__ DA) {
    int gid = blockIdx.x * 256 + threadIdx.x;
    if (gid >= 2 * NROWS * NHEADS) return;
    int h = gid & 15;
    int row = (gid >> 4) & (NROWS - 1);
    int dir = gid >> 18;
    float dtb = (dir ? bdtb : fdtb)[h];
    float Al = (dir ? bAl : fAl)[h];
    float x = bf2f(XBCDT[(size_t)(dir * NROWS + row) * XBCW + CONVDIM + h]) + dtb;
    float dt = (x > 15.f) ? x : log1pf(__expf(x));
    float dA = __expf(-__expf(Al) * dt);
    DT[gid] = dt;
    DA[gid] = dA;
}

// ---------------- scan pass A: per-chunk local state + decay product ----------------
__global__ __launch_bounds__(64) void k_scan_state(const unsigned short* __restrict__ XS,
                                                   const float* __restrict__ BCb,
                                                   const float* __restrict__ DT,
                                                   const float* __restrict__ DA,
                                                   float* __restrict__ S, float* __restrict__ P) {
    int idx = blockIdx.x;  // (((dir*8+b)*16+h)*16+chunk)
    int c = idx & 15, h = (idx >> 4) & 15, b = (idx >> 8) & 7, dir = idx >> 11;
    int p = threadIdx.x;
    const unsigned short* xs = XS + (size_t)dir * NROWS * DINNER;
    const float* bc = BCb + (size_t)dir * NROWS * 32;
    const float* dtp = DT + (size_t)dir * NROWS * NHEADS;
    const float* dap = DA + (size_t)dir * NROWS * NHEADS;
    float hreg[16];
#pragma unroll
    for (int n = 0; n < 16; n++) hreg[n] = 0.f;
    float Pp = 1.f;
#pragma unroll 4
    for (int tl = 0; tl < CHLEN; ++tl) {
        int t = c * CHLEN + tl;
        int l = dir ? (L_SEQ - 1 - t) : t;
        int row = (b << 11) + l;
        float xv = bf2f(xs[(size_t)row * DINNER + h * HEADDIM + p]);
        float dt = dtp[row * 16 + h];
        float dA = dap[row * 16 + h];
        f32x4 Bv[4];
#pragma unroll
        for (int qq = 0; qq < 4; qq++) Bv[qq] = *(const f32x4*)&bc[(size_t)row * 32 + qq * 4];
        float kk = dt * xv;
#pragma unroll
        for (int n = 0; n < 16; n++) hreg[n] = fmaf(hreg[n], dA, kk * Bv[n >> 2][n & 3]);
        Pp *= dA;
    }
#pragma unroll
    for (int qq = 0; qq < 4; qq++) {
        f32x4 v = {hreg[qq * 4], hreg[qq * 4 + 1], hreg[qq * 4 + 2], hreg[qq * 4 + 3]};
        *(f32x4*)&S[(size_t)idx * 1024 + p * 16 + qq * 4] = v;
    }
    if (p == 0) P[idx] = Pp;
}

// ---------------- scan pass B: combine chunk states IN PLACE (S -> Hinit) --------
__global__ void k_combine(float* __restrict__ S, const float* __restrict__ P) {
    int gid = blockIdx.x * 256 + threadIdx.x;  // 2*8*16*1024 = 262144
    if (gid >= 2 * 8 * 16 * 1024) return;
    int pn = gid & 1023;
    int base = gid >> 10;
    float H = 0.f;
#pragma unroll 4
    for (int c = 0; c < NCH; c++) {
        size_t o = ((size_t)base * NCH + c) * 1024 + pn;
        float s = S[o];   // read BEFORE overwrite
        S[o] = H;         // S becomes Hinit
        H = H * P[base * NCH + c] + s;
    }
}

// ---------------- scan pass C: replay with init state, emit y (bf16, aliases XS) ----
__global__ __launch_bounds__(64) void k_scan_out(const unsigned short* __restrict__ XS,
                                                 const float* __restrict__ BCb,
                                                 const float* __restrict__ DT,
                                                 const float* __restrict__ DA,
                                                 const float* __restrict__ Hinit,
                                                 const float* __restrict__ fDp,
                                                 const float* __restrict__ bDp,
                                                 unsigned short* __restrict__ Y) {
    int idx = blockIdx.x;
    int c = idx & 15, h = (idx >> 4) & 15, b = (idx >> 8) & 7, dir = idx >> 11;
    int p = threadIdx.x;
    const unsigned short* xs = XS + (size_t)dir * NROWS * DINNER;
    const float* bc = BCb + (size_t)dir * NROWS * 32;
    const float* dtp = DT + (size_t)dir * NROWS * NHEADS;
    const float* dap = DA + (size_t)dir * NROWS * NHEADS;
    unsigned short* yo = Y + (size_t)dir * NROWS * DINNER;
    float Dpv = (dir ? bDp : fDp)[h];
    float hreg[16];
#pragma unroll
    for (int qq = 0; qq < 4; qq++) {
        f32x4 v = *(const f32x4*)&Hinit[(size_t)idx * 1024 + p * 16 + qq * 4];
#pragma unroll
        for (int e = 0; e < 4; e++) hreg[qq * 4 + e] = v[e];
    }
#pragma unroll 4
    for (int tl = 0; tl < CHLEN; ++tl) {
        int t = c * CHLEN + tl;
        int l = dir ? (L_SEQ - 1 - t) : t;
        int row = (b << 11) + l;
        float xv = bf2f(xs[(size_t)row * DINNER + h * HEADDIM + p]);
        float dt = dtp[row * 16 + h];
        float dA = dap[row * 16 + h];
        f32x4 Bv[4], Cv[4];
#pragma unroll
        for (int qq = 0; qq < 4; qq++) Bv[qq] = *(const f32x4*)&bc[(size_t)row * 32 + qq * 4];
#pragma unroll
        for (int qq = 0; qq < 4; qq++) Cv[qq] = *(const f32x4*)&bc[(size_t)row * 32 + 16 + qq * 4];
        float kk = dt * xv;
        float y = 0.f;
#pragma unroll
        for (int n = 0; n < 16; n++) {
            hreg[n] = fmaf(hreg[n], dA, kk * Bv[n >> 2][n & 3]);
            y = fmaf(hreg[n], Cv[n >> 2][n & 3], y);
        }
        yo[(size_t)row * DINNER + h * HEADDIM + p] = f2bf(y + xv * Dpv);
    }
}

// ---------------- gated RMSNorm -> bf16 concat (2 rows/block, 16B loads) -----------
__global__ __launch_bounds__(256) void k_gatenorm(const unsigned short* __restrict__ Y,
                                                  const unsigned short* __restrict__ ZG,
                                                  const float* __restrict__ fnw,
                                                  const float* __restrict__ bnw,
                                                  unsigned short* __restrict__ NRM) {
    int bid = blockIdx.x;           // 0..16383
    int t = threadIdx.x;
    int sub = t >> 7;               // which of 2 rows
    int tt = t & 127;
    int rid = bid * 2 + sub;        // 0..32767
    int dir = rid >> 14;
    int row = rid & (NROWS - 1);
    int c = tt * 8;
    const size_t base = (size_t)(dir * NROWS + row) * DINNER + c;
    uint4 yu = *(const uint4*)&Y[base];
    uint4 zu = *(const uint4*)&ZG[base];
    float v[8];
    {
        const unsigned int yw[4] = {yu.x, yu.y, yu.z, yu.w};
        const unsigned int zw[4] = {zu.x, zu.y, zu.z, zu.w};
#pragma unroll
        for (int e = 0; e < 4; e++) {
            v[e * 2]     = bf2f((unsigned short)(yw[e] & 0xffff)) * silu(bf2f((unsigned short)(zw[e] & 0xffff)));
            v[e * 2 + 1] = bf2f((unsigned short)(yw[e] >> 16))    * silu(bf2f((unsigned short)(zw[e] >> 16)));
        }
    }
    float ss = 0.f;
#pragma unroll
    for (int e = 0; e < 8; e++) ss += v[e] * v[e];
#pragma unroll
    for (int off = 32; off > 0; off >>= 1) ss += __shfl_down(ss, off);
    __shared__ float red[4];
    if ((t & 63) == 0) red[t >> 6] = ss;
    __syncthreads();
    float tot = red[sub * 2] + red[sub * 2 + 1];
    float scale = rsqrtf(tot * (1.f / 1024.f) + 1e-5f);
    const float* nw = (dir ? bnw : fnw) + c;
    f32x4 nw0 = *(const f32x4*)&nw[0];
    f32x4 nw1 = *(const f32x4*)&nw[4];
    unsigned int ow[4];
#pragma unroll
    for (int e = 0; e < 4; e++) {
        float a = v[e * 2]     * scale * (e < 2 ? nw0[e * 2]     : nw1[(e - 2) * 2]);
        float b = v[e * 2 + 1] * scale * (e < 2 ? nw0[e * 2 + 1] : nw1[(e - 2) * 2 + 1]);
        ow[e] = (unsigned int)f2bf(a) | ((unsigned int)f2bf(b) << 16);
    }
    uint4 o = {ow[0], ow[1], ow[2], ow[3]};
    *(uint4*)&NRM[(size_t)row * 2048 + dir * DINNER + c] = o;
}

// ---------------- host launch ----------------
extern "C" void kernel_launch(void* const* d_in, const int* in_sizes, int n_in,
                              void* d_out, int out_size, void* d_ws, size_t ws_size,
                              hipStream_t stream) {
    const float* x     = (const float*)d_in[0];
    const float* f_inw = (const float*)d_in[1];
    const float* f_cw  = (const float*)d_in[2];
    const float* f_cb  = (const float*)d_in[3];
    const float* f_dtb = (const float*)d_in[4];
    const float* f_Al  = (const float*)d_in[5];
    const float* f_Dp  = (const float*)d_in[6];
    const float* f_nw  = (const float*)d_in[7];
    const float* f_ow  = (const float*)d_in[8];
    const float* b_inw = (const float*)d_in[9];
    const float* b_cw  = (const float*)d_in[10];
    const float* b_cb  = (const float*)d_in[11];
    const float* b_dtb = (const float*)d_in[12];
    const float* b_Al  = (const float*)d_in[13];
    const float* b_Dp  = (const float*)d_in[14];
    const float* b_nw  = (const float*)d_in[15];
    const float* b_ow  = (const float*)d_in[16];

    char* ws = (char*)d_ws;
    size_t off = 0;
    auto alloc = [&](size_t bytes) {
        void* p = ws + off;
        off += (bytes + 255) & ~(size_t)255;
        return p;
    };
    // --- persistent-phase buffers ---
    // union: XBCDT (in_proj -> conv/dt) / NRM (gatenorm -> out GEMM)
    unsigned short* XBCDT = (unsigned short*)alloc((size_t)2 * NROWS * XBCW * 2);   // 70.3 MB
    unsigned short* NRM   = XBCDT;  // 67.1 MB <= 70.3 MB, disjoint lifetime
    // union: XS (conv -> scans) / Y (scan C writes over XS element-after-read)
    unsigned short* XS    = (unsigned short*)alloc((size_t)2 * NROWS * DINNER * 2); // 67.1 MB
    unsigned short* Yb    = XS;
    unsigned short* ZG    = (unsigned short*)alloc((size_t)2 * NROWS * DINNER * 2); // 67.1 MB
    unsigned short* W2    = (unsigned short*)alloc((size_t)512 * 2048 * 2);         //  2.1 MB
    float* BCb  = (float*)alloc((size_t)2 * NROWS * 32 * 4);                        //  4.2 MB
    float* DT   = (float*)alloc((size_t)2 * NROWS * NHEADS * 4);                    //  2.1 MB
    float* DA   = (float*)alloc((size_t)2 * NROWS * NHEADS * 4);                    //  2.1 MB
    // union: {XB, W1} (phase 0-1) / {S, P} (phase 4) — disjoint lifetimes
    char* unionBase = (char*)alloc((size_t)16777216 + (size_t)NPROJ_P * DMODEL * 2); // 21.1 MB
    unsigned short* XB = (unsigned short*)unionBase;
    unsigned short* W1 = (unsigned short*)(unionBase + 16777216);
    float* S = (float*)unionBase;                    // 16.8 MB (Hinit in-place)
    float* P = (float*)(unionBase + 16777216);       // 16 KB
    // total: ~236 MB

    if (ws_size < off) return;  // defensive: fail cleanly (wrong answer) instead of faulting

    // 1. merged prepack
    {
        int n = PREP_N1 + PREP_N2 + PREP_N3;
        k_prep<<<(n + 255) / 256, 256, 0, stream>>>(x, f_inw, b_inw, f_ow, b_ow, XB, W1, W2);
    }
    // 2. in_proj GEMM (both dirs), XCD-swizzled pipelined, routed bf16 epilogue
    k_gemm_proj<<<8 * 32 * 33, 256, 0, stream>>>(XB, W1, ZG, XBCDT);
    // 3. LDS-tiled conv + dt prep
    k_conv2<<<5 * 2 * 8 * 32, 256, 0, stream>>>(XBCDT, f_cw, f_cb, b_cw, b_cb, XS, BCb);
    {
        int n = 2 * NROWS * NHEADS;
        k_dt<<<(n + 255) / 256, 256, 0, stream>>>(XBCDT, f_dtb, f_Al, b_dtb, b_Al, DT, DA);
    }
    // 4. chunked scan (S written over dead XB/W1 region; combine is in-place)
    k_scan_state<<<2 * 8 * 16 * NCH, 64, 0, stream>>>(XS, BCb, DT, DA, S, P);
    {
        int n = 2 * 8 * 16 * 1024;
        k_combine<<<(n + 255) / 256, 256, 0, stream>>>(S, P);
    }
    k_scan_out<<<2 * 8 * 16 * NCH, 64, 0, stream>>>(XS, BCb, DT, DA, S, f_Dp, b_Dp, Yb);
    // 5. gated RMSNorm -> bf16 (writes NRM over dead XBCDT region)
    k_gatenorm<<<NROWS, 256, 0, stream>>>(Yb, ZG, f_nw, b_nw, NRM);
    // 6. out_proj GEMM (both dirs summed via K-concat), XCD-swizzled -> d_out
    k_gemm_out<<<8 * 32 * 4, 256, 0, stream>>>(NRM, W2, (float*)d_out);
}